// Round 4
// baseline (102.938 us; speedup 1.0000x reference)
//
#include <hip/hip_runtime.h>
#include <math.h>

#define BLOCK 256
#define QPT   4      // queries per thread in the values pass (4 => 4 blocks/CU)
#define CHUNK 512    // max refs staged per LDS chunk (8 KB of float4)
#define S     64     // slices == wave width (one ballot bit per slice)
#define DELTA 0.05f  // conservative slack for deferred-an slice mins (see below)

typedef float f32x2 __attribute__((ext_vector_type(2)));

// Rounding-exact helpers: match numpy's mul-then-add rounding exactly.
__device__ __forceinline__ float mul_rn(float a, float b) {
#pragma clang fp contract(off)
    return a * b;
}
__device__ __forceinline__ float add_rn(float a, float b) {
#pragma clang fp contract(off)
    return a + b;
}
__device__ __forceinline__ float sumsq3(float x, float y, float z) {
    return add_rn(add_rn(mul_rn(x, x), mul_rn(y, y)), mul_rn(z, z));
}
__device__ __forceinline__ float med3f(float a, float b, float c) {
    return __builtin_amdgcn_fmed3f(a, b, c);
}

// In-place top-3 VALUES update: write order d2 <- d1 <- d0 needs NO temps.
__device__ __forceinline__ void val3_push(float& d0, float& d1, float& d2, float v) {
    d2 = med3f(d1, d2, v);
    d1 = med3f(d0, d1, v);
    d0 = fminf(d0, v);
}

// Lexicographic (sq, idx) top-3 insert — matches lax.top_k stability.
__device__ __forceinline__ void lex3_push(float& d0, float& d1, float& d2,
                                          int& i0, int& i1, int& i2,
                                          float sq, int idx) {
    const bool l0 = (sq < d0) || (sq == d0 && idx < i0);
    const bool l1 = (sq < d1) || (sq == d1 && idx < i1);
    const bool l2 = (sq < d2) || (sq == d2 && idx < i2);
    i2 = l1 ? i1 : (l2 ? idx : i2);
    d2 = l1 ? d1 : (l2 ? sq  : d2);
    i1 = l0 ? i0 : (l1 ? idx : i1);
    d1 = l0 ? d0 : (l1 ? sq  : d1);
    i0 = l0 ? idx : i0;
    d0 = l0 ? sq  : d0;
}

// Stage cnt refs (cnt % 4 == 0, start % 4 == 0).
// LDS layout is ref-pair SoA for packed-f32 consumption:
//   smem[2p]   = (x_{2p}, x_{2p+1}, y_{2p}, y_{2p+1})
//   smem[2p+1] = (z_{2p}, z_{2p+1}, w_{2p}, w_{2p+1})
// with (x,y,z) pre-scaled by -2 (EXACT, power-of-two) and w = ||b||^2.
// Packed halves land in aligned VGPR pairs straight off ds_read_b128.
// When g4 != nullptr (blockIdx.x == 0 blocks only), dual-store the
// transformed refs to global r4 in AoS layout for the rescan kernel.
__device__ __forceinline__ void stage_chunk(const float* __restrict__ r,
                                            int start, int cnt,
                                            float4* __restrict__ smem,
                                            float4* __restrict__ g4) {
    const int t = threadIdx.x;
    if (t < (cnt >> 2)) {
        const float4* p = (const float4*)(r + (size_t)(start + t * 4) * 3);
        const float4 A = p[0], B = p[1], C = p[2];
        const float4 o0 = make_float4(-2.0f * A.x, -2.0f * A.y, -2.0f * A.z,
                                      sumsq3(A.x, A.y, A.z));
        const float4 o1 = make_float4(-2.0f * A.w, -2.0f * B.x, -2.0f * B.y,
                                      sumsq3(A.w, B.x, B.y));
        const float4 o2 = make_float4(-2.0f * B.z, -2.0f * B.w, -2.0f * C.x,
                                      sumsq3(B.z, B.w, C.x));
        const float4 o3 = make_float4(-2.0f * C.y, -2.0f * C.z, -2.0f * C.w,
                                      sumsq3(C.y, C.z, C.w));
        // transposed ref-pair SoA for the packed hot loop
        smem[t * 4 + 0] = make_float4(o0.x, o1.x, o0.y, o1.y);
        smem[t * 4 + 1] = make_float4(o0.z, o1.z, o0.w, o1.w);
        smem[t * 4 + 2] = make_float4(o2.x, o3.x, o2.y, o3.y);
        smem[t * 4 + 3] = make_float4(o2.z, o3.z, o2.w, o3.w);
        if (g4) {   // AoS for rescan
            g4[t * 4 + 0] = o0;
            g4[t * 4 + 1] = o1;
            g4[t * 4 + 2] = o2;
            g4[t * 4 + 3] = o3;
        }
    }
}

// Pass 1: per (query, slice) approximate min of sq, `an` deferred out of
// the loop (min_j[(an+bw)-2dot] = an + min_j[bw-2dot] + O(5e-3) drift,
// absorbed by DELTA in pass 2).
//
// R3 arithmetic fix: refsPerSlice=256 <= CHUNK so the chunk loop runs ONCE;
// LDS traffic is 16.8 MB total (~0.24 us chip-wide) — values is purely
// VALU-ISSUE-bound (28 VALU/2-ref iter ~ 12 us floor). This round packs the
// fma chain into VOP3P v_pk_fma_f32 via float2 elementwise fma:
// 3 pk_fma + 1 v_min3 = 4 issue slots per 2 refs per query (was 7).
// Bit-identical smin: each packed half runs the exact same fma chain.
__global__ __launch_bounds__(BLOCK, 4) void values_kernel(
    const float* __restrict__ q, const float* __restrict__ r,
    float* __restrict__ smin, float4* __restrict__ r4,
    int N, int refsPerSlice)
{
    __shared__ float4 smem[CHUNK];
    const int tid = threadIdx.x;
    const int s   = blockIdx.y;
    const int start = s * refsPerSlice;

    f32x2 ax[QPT], ay[QPT], az[QPT];
    float an[QPT], dm[QPT];
#pragma unroll
    for (int u = 0; u < QPT; ++u) {
        const int qi = (blockIdx.x * QPT + u) * BLOCK + tid;
        const float a0 = q[qi * 3 + 0];
        const float a1 = q[qi * 3 + 1];
        const float a2 = q[qi * 3 + 2];
        ax[u] = (f32x2){a0, a0};
        ay[u] = (f32x2){a1, a1};
        az[u] = (f32x2){a2, a2};
        an[u] = sumsq3(a0, a1, a2);
        dm[u] = __builtin_inff();
    }

    for (int coff = 0; coff < refsPerSlice; coff += CHUNK) {
        const int cnt = min(CHUNK, refsPerSlice - coff);   // cnt % 4 == 0
        __syncthreads();
        stage_chunk(r, start + coff, cnt, smem,
                    (blockIdx.x == 0) ? (r4 + start + coff) : nullptr);
        __syncthreads();
#pragma unroll 4
        for (int j = 0; j < cnt; j += 2) {
            const float4 P = smem[j];       // (x0,x1,y0,y1)
            const float4 Q = smem[j + 1];   // (z0,z1,w0,w1)
            const f32x2 xx = (f32x2){P.x, P.y};
            const f32x2 yy = (f32x2){P.z, P.w};
            const f32x2 zz = (f32x2){Q.x, Q.y};
            const f32x2 ww = (f32x2){Q.z, Q.w};
#pragma unroll
            for (int u = 0; u < QPT; ++u) {
                const f32x2 t = __builtin_elementwise_fma(az[u], zz,
                                __builtin_elementwise_fma(ay[u], yy,
                                __builtin_elementwise_fma(ax[u], xx, ww)));
                dm[u] = fminf(fminf(t.x, t.y), dm[u]);   // -> v_min3_f32
            }
        }
    }

#pragma unroll
    for (int u = 0; u < QPT; ++u) {
        const int qi = (blockIdx.x * QPT + u) * BLOCK + tid;
        smin[(size_t)qi * S + s] = an[u] + dm[u];   // fold an back in once
    }
}

// Pass 2: ONE WAVE PER QUERY, all in-register:
//  A) lane s reads slice s's (approx) min — coalesced 256 B/wave;
//     butterfly-reduce the 3 smallest -> g2 = 3rd-smallest slice-min.
//  B) mask = ballot(v <= g2 + DELTA): covers every slice containing a true
//     top-3 member (g2 >= true 3rd-smallest sq; DELTA >> deferred-an
//     drift). popcount ~3-4. Lanes cooperatively rescan those slices from
//     the PRE-TRANSFORMED r4 (one coalesced dwordx4/ref). BIT-EXACT vs
//     reference: -2 is a power of two, so rounding commutes through the
//     scaled chain => chain == -2*dot_ref exactly, and
//     add_rn(-2dot, add_rn(an,bw)) == fma(-2, dot, add_rn(an,bw)).
//     Per-lane strict-< top-3 (ascending-idx stream) then a lexicographic
//     butterfly merge == lax.top_k exactly.
//  C) lane 0: rounding-exact weights + flow gather + store.
__global__ __launch_bounds__(BLOCK, 4) void rescan_kernel(
    const float* __restrict__ q, const float4* __restrict__ r4,
    const float* __restrict__ smin, const float* __restrict__ flow,
    float* __restrict__ out, int N, int refsPerSlice)
{
    const int lane = threadIdx.x & 63;
    const int qi   = blockIdx.x * (BLOCK / 64) + (threadIdx.x >> 6);

    const float a0 = q[qi * 3 + 0];
    const float a1 = q[qi * 3 + 1];
    const float a2 = q[qi * 3 + 2];
    const float an = sumsq3(a0, a1, a2);

    // --- A: coalesced min load + butterfly 3-smallest reduce ---
    const float v = smin[(size_t)qi * S + lane];
    float g0 = v, g1 = __builtin_inff(), g2 = __builtin_inff();
#pragma unroll
    for (int m = 1; m < 64; m <<= 1) {
        const float e0 = __shfl_xor(g0, m);
        const float e1 = __shfl_xor(g1, m);
        const float e2 = __shfl_xor(g2, m);
        val3_push(g0, g1, g2, e0);
        val3_push(g0, g1, g2, e1);
        val3_push(g0, g1, g2, e2);
    }

    unsigned long long mask = __ballot(v <= g2 + DELTA);

    // --- B: cooperative exact rescan of contributing slices ---
    float d0 = __builtin_inff(), d1 = __builtin_inff(), d2 = __builtin_inff();
    int   i0 = 0x7fffffff, i1 = 0x7fffffff, i2 = 0x7fffffff;
    const int K = refsPerSlice >> 6;       // refs per lane per slice

    while (mask) {
        const int s = (int)__builtin_ctzll(mask);
        mask &= mask - 1;
        const int base = s * refsPerSlice;
#pragma unroll 4
        for (int k = 0; k < K; ++k) {
            const int idx = base + lane + (k << 6);   // ascending per lane
            const float4 b = r4[idx];                 // (-2x,-2y,-2z,||b||^2)
            const float d = __builtin_fmaf(a2, b.z,
                            __builtin_fmaf(a1, b.y, mul_rn(a0, b.x)));
            const float sq = add_rn(d, add_rn(an, b.w));   // == reference fma(-2,dot,s)
            const bool c0 = sq < d0;
            const bool c1 = sq < d1;
            const bool c2 = sq < d2;
            i2 = c1 ? i1 : (c2 ? idx : i2);
            d2 = c1 ? d1 : (c2 ? sq  : d2);
            i1 = c0 ? i0 : (c1 ? idx : i1);
            d1 = c0 ? d0 : (c1 ? sq  : d1);
            i0 = c0 ? idx : i0;
            d0 = c0 ? sq  : d0;
        }
    }

    // lexicographic butterfly merge across the 64 lanes
#pragma unroll
    for (int m = 1; m < 64; m <<= 1) {
        const float e0 = __shfl_xor(d0, m);
        const float e1 = __shfl_xor(d1, m);
        const float e2 = __shfl_xor(d2, m);
        const int   j0 = __shfl_xor(i0, m);
        const int   j1 = __shfl_xor(i1, m);
        const int   j2 = __shfl_xor(i2, m);
        lex3_push(d0, d1, d2, i0, i1, i2, e0, j0);
        lex3_push(d0, d1, d2, i0, i1, i2, e1, j1);
        lex3_push(d0, d1, d2, i0, i1, i2, e2, j2);
    }

    // --- C: epilogue (rounding-exact, matches reference op order) ---
    if (lane == 0) {
        const float t0 = sqrtf(fmaxf(d0, 1e-12f));
        const float t1 = sqrtf(fmaxf(d1, 1e-12f));
        const float t2 = sqrtf(fmaxf(d2, 1e-12f));
        const float w0r = 1.0f / add_rn(t0, 1e-8f);
        const float w1r = 1.0f / add_rn(t1, 1e-8f);
        const float w2r = 1.0f / add_rn(t2, 1e-8f);
        const float wsum = add_rn(add_rn(w0r, w1r), w2r);
        const float w0 = w0r / wsum;
        const float w1 = w1r / wsum;
        const float w2 = w2r / wsum;

        const float f00 = flow[3 * i0 + 0], f01 = flow[3 * i0 + 1], f02 = flow[3 * i0 + 2];
        const float f10 = flow[3 * i1 + 0], f11 = flow[3 * i1 + 1], f12 = flow[3 * i1 + 2];
        const float f20 = flow[3 * i2 + 0], f21 = flow[3 * i2 + 1], f22 = flow[3 * i2 + 2];

        out[qi * 3 + 0] = add_rn(add_rn(mul_rn(w0, f00), mul_rn(w1, f10)), mul_rn(w2, f20));
        out[qi * 3 + 1] = add_rn(add_rn(mul_rn(w0, f01), mul_rn(w1, f11)), mul_rn(w2, f21));
        out[qi * 3 + 2] = add_rn(add_rn(mul_rn(w0, f02), mul_rn(w1, f12)), mul_rn(w2, f22));
    }
}

extern "C" void kernel_launch(void* const* d_in, const int* in_sizes, int n_in,
                              void* d_out, int out_size, void* d_ws, size_t ws_size,
                              hipStream_t stream) {
    const float* q    = (const float*)d_in[0];
    const float* r    = (const float*)d_in[1];
    const float* flow = (const float*)d_in[2];
    // d_in[3] is k (==3), hard-coded.

    const int N = in_sizes[0] / 3;
    const int M = in_sizes[1] / 3;

    // ws layout: [smin: N*S floats][r4: M float4]
    const int refsPerSlice = M / S;
    float*  smin = (float*)d_ws;
    float4* r4   = (float4*)((char*)d_ws + (size_t)N * S * sizeof(float));
    (void)ws_size;

    dim3 grid1(N / (BLOCK * QPT), S);
    values_kernel<<<grid1, BLOCK, 0, stream>>>(q, r, smin, r4, N, refsPerSlice);

    rescan_kernel<<<N / (BLOCK / 64), BLOCK, 0, stream>>>(
        q, r4, smin, flow, (float*)d_out, N, refsPerSlice);
}

// Round 5
// 96.330 us; speedup vs baseline: 1.0686x; 1.0686x over previous
//
#include <hip/hip_runtime.h>
#include <math.h>

#define BLOCK 256
#define S     64     // slices == wave width (one ballot bit per slice)
#define DELTA 0.5f   // >= 2*E for the f16-MFMA approx pass (E<=~0.14; see below)

typedef _Float16 half8 __attribute__((ext_vector_type(8)));
typedef float    f32x16 __attribute__((ext_vector_type(16)));

// Rounding-exact helpers: match numpy's mul-then-add rounding exactly.
__device__ __forceinline__ float mul_rn(float a, float b) {
#pragma clang fp contract(off)
    return a * b;
}
__device__ __forceinline__ float add_rn(float a, float b) {
#pragma clang fp contract(off)
    return a + b;
}
__device__ __forceinline__ float sumsq3(float x, float y, float z) {
    return add_rn(add_rn(mul_rn(x, x), mul_rn(y, y)), mul_rn(z, z));
}
__device__ __forceinline__ float med3f(float a, float b, float c) {
    return __builtin_amdgcn_fmed3f(a, b, c);
}

// In-place top-3 VALUES update: write order d2 <- d1 <- d0 needs NO temps.
__device__ __forceinline__ void val3_push(float& d0, float& d1, float& d2, float v) {
    d2 = med3f(d1, d2, v);
    d1 = med3f(d0, d1, v);
    d0 = fminf(d0, v);
}

// Lexicographic (sq, idx) top-3 insert — matches lax.top_k stability.
__device__ __forceinline__ void lex3_push(float& d0, float& d1, float& d2,
                                          int& i0, int& i1, int& i2,
                                          float sq, int idx) {
    const bool l0 = (sq < d0) || (sq == d0 && idx < i0);
    const bool l1 = (sq < d1) || (sq == d1 && idx < i1);
    const bool l2 = (sq < d2) || (sq == d2 && idx < i2);
    i2 = l1 ? i1 : (l2 ? idx : i2);
    d2 = l1 ? d1 : (l2 ? sq  : d2);
    i1 = l0 ? i0 : (l1 ? idx : i1);
    d1 = l0 ? d0 : (l1 ? sq  : d1);
    i0 = l0 ? idx : i0;
    d0 = l0 ? sq  : d0;
}

// min of 16 accumulator lanes -> v_min3 tree (8 ops)
__device__ __forceinline__ float fold16(const f32x16 c) {
    const float A = fminf(fminf(c[0],  c[1]),  c[2]);
    const float B = fminf(fminf(c[3],  c[4]),  c[5]);
    const float C = fminf(fminf(c[6],  c[7]),  c[8]);
    const float D = fminf(fminf(c[9],  c[10]), c[11]);
    const float E = fminf(fminf(c[12], c[13]), c[14]);
    const float F = fminf(fminf(A, B), C);
    const float G = fminf(fminf(D, E), c[15]);
    return fminf(F, G);
}

// Pass 1 (MFMA): per (query, slice) approximate min of sq via ONE
// v_mfma_f32_32x32x16_f16 per 32ref x 32query tile. K-slot packing does
// fp16 hi/lo error correction IN the K dimension (m = -2p, q = query):
//   k0..2 : mh_i (A)  * qh_i (B)
//   k3..5 : mh_i (A)  * ql_i (B)
//   k6..8 : ml_i (A)  * qh_i (B)
//   k9,k10: pwh,pwl(A)* 1.0  (B)     k11..15: 0
// => D[p][q] = ||p||^2 - 2 p.q + eps, |eps| <= ~0.14 worst case
// (dropped ml*ql <= 0.006, pw residual <= 0.003, f32 accum rounding
// <= ~0.13). DELTA = 0.5 >= 2E covers the ballot mask.
//
// Fragment layout ASSUMED (flip A/B k-map next round if refcheck fails):
//   A: lane l -> row l&31, k = 8*(l>>5) + j   (j = elem 0..7)
//   B: lane l -> col l&31, k = 8*(l>>5) + j
//   C/D (HW-verified m74/m101): col = lane&31,
//        row = (reg&3) + 8*(reg>>2) + 4*(lane>>5)
//
// Block = 256 thr = 4 waves, ONE slice, 256 queries (64/wave as two
// 32-col B-frags sharing each A-frag ds_read). A-frags staged in LDS
// (8 tiles x 64 lanes x 16B = 8KB), reused by all 4 waves.
__global__ __launch_bounds__(BLOCK) void values_kernel(
    const float* __restrict__ q, const float* __restrict__ r,
    float* __restrict__ smin, float4* __restrict__ r4,
    int N, int refsPerSlice)
{
    __shared__ half8 afrag[8][64];
    const int tid = threadIdx.x;
    const int s   = blockIdx.y;
    const int start = s * refsPerSlice;

    // ---- stage A-fragments (+ dual-store exact f32 r4 for the rescan) ----
    for (int j = tid; j < refsPerSlice; j += BLOCK) {
        const float px = r[3 * (start + j) + 0];
        const float py = r[3 * (start + j) + 1];
        const float pz = r[3 * (start + j) + 2];
        const float mx = -2.0f * px, my = -2.0f * py, mz = -2.0f * pz;
        const float pw = sumsq3(px, py, pz);
        const _Float16 mhx = (_Float16)mx, mhy = (_Float16)my, mhz = (_Float16)mz;
        const _Float16 mlx = (_Float16)(mx - (float)mhx);
        const _Float16 mly = (_Float16)(my - (float)mhy);
        const _Float16 mlz = (_Float16)(mz - (float)mhz);
        const _Float16 pwh = (_Float16)pw;
        const _Float16 pwl = (_Float16)(pw - (float)pwh);
        half8 lo, hi;
        lo[0] = mhx; lo[1] = mhy; lo[2] = mhz; lo[3] = mhx;
        lo[4] = mhy; lo[5] = mhz; lo[6] = mlx; lo[7] = mly;
        hi[0] = mlz; hi[1] = pwh; hi[2] = pwl; hi[3] = (_Float16)0;
        hi[4] = (_Float16)0; hi[5] = (_Float16)0; hi[6] = (_Float16)0; hi[7] = (_Float16)0;
        afrag[j >> 5][(j & 31)]      = lo;   // k 0..7 half
        afrag[j >> 5][32 + (j & 31)] = hi;   // k 8..15 half
        if (blockIdx.x == 0)   // bit-identical to previous rounds' r4
            r4[start + j] = make_float4(mx, my, mz, pw);
    }
    __syncthreads();

    // ---- wave compute: 64 queries/wave = two 32-col B operands ----
    const int lane = tid & 63, wave = tid >> 6, col = lane & 31;
    const int q0 = blockIdx.x * 256 + wave * 64 + col;
    const int q1 = q0 + 32;

    const float a0x = q[q0 * 3 + 0], a0y = q[q0 * 3 + 1], a0z = q[q0 * 3 + 2];
    const float a1x = q[q1 * 3 + 0], a1y = q[q1 * 3 + 1], a1z = q[q1 * 3 + 2];
    const float an0 = sumsq3(a0x, a0y, a0z);
    const float an1 = sumsq3(a1x, a1y, a1z);

    const _Float16 q0hx = (_Float16)a0x, q0hy = (_Float16)a0y, q0hz = (_Float16)a0z;
    const _Float16 q0lx = (_Float16)(a0x - (float)q0hx);
    const _Float16 q0ly = (_Float16)(a0y - (float)q0hy);
    const _Float16 q0lz = (_Float16)(a0z - (float)q0hz);
    const _Float16 q1hx = (_Float16)a1x, q1hy = (_Float16)a1y, q1hz = (_Float16)a1z;
    const _Float16 q1lx = (_Float16)(a1x - (float)q1hx);
    const _Float16 q1ly = (_Float16)(a1y - (float)q1hy);
    const _Float16 q1lz = (_Float16)(a1z - (float)q1hz);
    const _Float16 one = (_Float16)1.0f, zer = (_Float16)0.0f;

    half8 b0, b1;
    if (lane < 32) {   // k 0..7 half of the B column
        b0[0]=q0hx; b0[1]=q0hy; b0[2]=q0hz; b0[3]=q0lx; b0[4]=q0ly; b0[5]=q0lz; b0[6]=q0hx; b0[7]=q0hy;
        b1[0]=q1hx; b1[1]=q1hy; b1[2]=q1hz; b1[3]=q1lx; b1[4]=q1ly; b1[5]=q1lz; b1[6]=q1hx; b1[7]=q1hy;
    } else {           // k 8..15 half
        b0[0]=q0hz; b0[1]=one; b0[2]=one; b0[3]=zer; b0[4]=zer; b0[5]=zer; b0[6]=zer; b0[7]=zer;
        b1[0]=q1hz; b1[1]=one; b1[2]=one; b1[3]=zer; b1[4]=zer; b1[5]=zer; b1[6]=zer; b1[7]=zer;
    }

    const f32x16 Z = {0.f,0.f,0.f,0.f,0.f,0.f,0.f,0.f,0.f,0.f,0.f,0.f,0.f,0.f,0.f,0.f};
    float rm0 = __builtin_inff(), rm1 = __builtin_inff();
    const int nt = refsPerSlice >> 5;
#pragma unroll 4
    for (int t = 0; t < nt; ++t) {
        const half8 af = afrag[t][lane];                       // ds_read_b128
        const f32x16 c0 = __builtin_amdgcn_mfma_f32_32x32x16_f16(af, b0, Z, 0, 0, 0);
        const f32x16 c1 = __builtin_amdgcn_mfma_f32_32x32x16_f16(af, b1, Z, 0, 0, 0);
        rm0 = fminf(rm0, fold16(c0));
        rm1 = fminf(rm1, fold16(c1));
    }
    // lanes l and l^32 hold complementary ROW halves of the same col
    rm0 = fminf(rm0, __shfl_xor(rm0, 32));
    rm1 = fminf(rm1, __shfl_xor(rm1, 32));

    if (lane < 32) smin[(size_t)q0 * S + s] = an0 + rm0;
    else           smin[(size_t)q1 * S + s] = an1 + rm1;
}

// Pass 2: ONE WAVE PER QUERY, all in-register (UNCHANGED except DELTA):
//  A) lane s reads slice s's (approx) min; butterfly-reduce 3 smallest.
//  B) mask = ballot(v <= g2 + DELTA) — DELTA=0.5 >= 2*E_mfma covers every
//     slice containing a true top-3 member. Cooperative EXACT rescan from
//     r4 (bit-exact reference rounding; see R3 proof), strict-< top-3 then
//     lexicographic butterfly merge == lax.top_k exactly.
//  C) lane 0: rounding-exact weights + flow gather + store.
__global__ __launch_bounds__(BLOCK, 4) void rescan_kernel(
    const float* __restrict__ q, const float4* __restrict__ r4,
    const float* __restrict__ smin, const float* __restrict__ flow,
    float* __restrict__ out, int N, int refsPerSlice)
{
    const int lane = threadIdx.x & 63;
    const int qi   = blockIdx.x * (BLOCK / 64) + (threadIdx.x >> 6);

    const float a0 = q[qi * 3 + 0];
    const float a1 = q[qi * 3 + 1];
    const float a2 = q[qi * 3 + 2];
    const float an = sumsq3(a0, a1, a2);

    // --- A: coalesced min load + butterfly 3-smallest reduce ---
    const float v = smin[(size_t)qi * S + lane];
    float g0 = v, g1 = __builtin_inff(), g2 = __builtin_inff();
#pragma unroll
    for (int m = 1; m < 64; m <<= 1) {
        const float e0 = __shfl_xor(g0, m);
        const float e1 = __shfl_xor(g1, m);
        const float e2 = __shfl_xor(g2, m);
        val3_push(g0, g1, g2, e0);
        val3_push(g0, g1, g2, e1);
        val3_push(g0, g1, g2, e2);
    }

    unsigned long long mask = __ballot(v <= g2 + DELTA);

    // --- B: cooperative exact rescan of contributing slices ---
    float d0 = __builtin_inff(), d1 = __builtin_inff(), d2 = __builtin_inff();
    int   i0 = 0x7fffffff, i1 = 0x7fffffff, i2 = 0x7fffffff;
    const int K = refsPerSlice >> 6;       // refs per lane per slice

    while (mask) {
        const int s = (int)__builtin_ctzll(mask);
        mask &= mask - 1;
        const int base = s * refsPerSlice;
#pragma unroll 4
        for (int k = 0; k < K; ++k) {
            const int idx = base + lane + (k << 6);   // ascending per lane
            const float4 b = r4[idx];                 // (-2x,-2y,-2z,||b||^2)
            const float d = __builtin_fmaf(a2, b.z,
                            __builtin_fmaf(a1, b.y, mul_rn(a0, b.x)));
            const float sq = add_rn(d, add_rn(an, b.w));   // == reference fma(-2,dot,s)
            const bool c0 = sq < d0;
            const bool c1 = sq < d1;
            const bool c2 = sq < d2;
            i2 = c1 ? i1 : (c2 ? idx : i2);
            d2 = c1 ? d1 : (c2 ? sq  : d2);
            i1 = c0 ? i0 : (c1 ? idx : i1);
            d1 = c0 ? d0 : (c1 ? sq  : d1);
            i0 = c0 ? idx : i0;
            d0 = c0 ? sq  : d0;
        }
    }

    // lexicographic butterfly merge across the 64 lanes
#pragma unroll
    for (int m = 1; m < 64; m <<= 1) {
        const float e0 = __shfl_xor(d0, m);
        const float e1 = __shfl_xor(d1, m);
        const float e2 = __shfl_xor(d2, m);
        const int   j0 = __shfl_xor(i0, m);
        const int   j1 = __shfl_xor(i1, m);
        const int   j2 = __shfl_xor(i2, m);
        lex3_push(d0, d1, d2, i0, i1, i2, e0, j0);
        lex3_push(d0, d1, d2, i0, i1, i2, e1, j1);
        lex3_push(d0, d1, d2, i0, i1, i2, e2, j2);
    }

    // --- C: epilogue (rounding-exact, matches reference op order) ---
    if (lane == 0) {
        const float t0 = sqrtf(fmaxf(d0, 1e-12f));
        const float t1 = sqrtf(fmaxf(d1, 1e-12f));
        const float t2 = sqrtf(fmaxf(d2, 1e-12f));
        const float w0r = 1.0f / add_rn(t0, 1e-8f);
        const float w1r = 1.0f / add_rn(t1, 1e-8f);
        const float w2r = 1.0f / add_rn(t2, 1e-8f);
        const float wsum = add_rn(add_rn(w0r, w1r), w2r);
        const float w0 = w0r / wsum;
        const float w1 = w1r / wsum;
        const float w2 = w2r / wsum;

        const float f00 = flow[3 * i0 + 0], f01 = flow[3 * i0 + 1], f02 = flow[3 * i0 + 2];
        const float f10 = flow[3 * i1 + 0], f11 = flow[3 * i1 + 1], f12 = flow[3 * i1 + 2];
        const float f20 = flow[3 * i2 + 0], f21 = flow[3 * i2 + 1], f22 = flow[3 * i2 + 2];

        out[qi * 3 + 0] = add_rn(add_rn(mul_rn(w0, f00), mul_rn(w1, f10)), mul_rn(w2, f20));
        out[qi * 3 + 1] = add_rn(add_rn(mul_rn(w0, f01), mul_rn(w1, f11)), mul_rn(w2, f21));
        out[qi * 3 + 2] = add_rn(add_rn(mul_rn(w0, f02), mul_rn(w1, f12)), mul_rn(w2, f22));
    }
}

extern "C" void kernel_launch(void* const* d_in, const int* in_sizes, int n_in,
                              void* d_out, int out_size, void* d_ws, size_t ws_size,
                              hipStream_t stream) {
    const float* q    = (const float*)d_in[0];
    const float* r    = (const float*)d_in[1];
    const float* flow = (const float*)d_in[2];
    // d_in[3] is k (==3), hard-coded.

    const int N = in_sizes[0] / 3;
    const int M = in_sizes[1] / 3;

    // ws layout: [smin: N*S floats][r4: M float4]
    const int refsPerSlice = M / S;
    float*  smin = (float*)d_ws;
    float4* r4   = (float4*)((char*)d_ws + (size_t)N * S * sizeof(float));
    (void)ws_size;

    dim3 grid1(N / 256, S);
    values_kernel<<<grid1, BLOCK, 0, stream>>>(q, r, smin, r4, N, refsPerSlice);

    rescan_kernel<<<N / (BLOCK / 64), BLOCK, 0, stream>>>(
        q, r4, smin, flow, (float*)d_out, N, refsPerSlice);
}

// Round 6
// 90.658 us; speedup vs baseline: 1.1355x; 1.0626x over previous
//
#include <hip/hip_runtime.h>
#include <math.h>

#define BLOCK 256
#define S     64     // slices == wave width (one ballot bit per slice)
#define DELTA 0.5f   // >= 2*E for the f16-MFMA approx pass (E<=~0.14; see below)

typedef _Float16 half8 __attribute__((ext_vector_type(8)));
typedef float    f32x16 __attribute__((ext_vector_type(16)));

// Rounding-exact helpers: match numpy's mul-then-add rounding exactly.
__device__ __forceinline__ float mul_rn(float a, float b) {
#pragma clang fp contract(off)
    return a * b;
}
__device__ __forceinline__ float add_rn(float a, float b) {
#pragma clang fp contract(off)
    return a + b;
}
__device__ __forceinline__ float sumsq3(float x, float y, float z) {
    return add_rn(add_rn(mul_rn(x, x), mul_rn(y, y)), mul_rn(z, z));
}
__device__ __forceinline__ float med3f(float a, float b, float c) {
    return __builtin_amdgcn_fmed3f(a, b, c);
}

// In-place top-3 VALUES update: write order d2 <- d1 <- d0 needs NO temps.
__device__ __forceinline__ void val3_push(float& d0, float& d1, float& d2, float v) {
    d2 = med3f(d1, d2, v);
    d1 = med3f(d0, d1, v);
    d0 = fminf(d0, v);
}

// butterfly u32 min across the wave
__device__ __forceinline__ int wave_min_i(int v) {
#pragma unroll
    for (int m = 1; m < 64; m <<= 1) v = min(v, __shfl_xor(v, m));
    return v;
}

// min of 16 accumulator lanes -> v_min3 tree (8 ops)
__device__ __forceinline__ float fold16(const f32x16 c) {
    const float A = fminf(fminf(c[0],  c[1]),  c[2]);
    const float B = fminf(fminf(c[3],  c[4]),  c[5]);
    const float C = fminf(fminf(c[6],  c[7]),  c[8]);
    const float D = fminf(fminf(c[9],  c[10]), c[11]);
    const float E = fminf(fminf(c[12], c[13]), c[14]);
    const float F = fminf(fminf(A, B), C);
    const float G = fminf(fminf(D, E), c[15]);
    return fminf(F, G);
}

// Pass 1 (MFMA): per (query, slice) approximate min of sq via ONE
// v_mfma_f32_32x32x16_f16 per 32ref x 32query tile. K-slot packing does
// fp16 hi/lo error correction IN the K dimension (m = -2p, q = query):
//   k0..2 : mh_i (A)  * qh_i (B)
//   k3..5 : mh_i (A)  * ql_i (B)
//   k6..8 : ml_i (A)  * qh_i (B)
//   k9,k10: pwh,pwl(A)* 1.0  (B)     k11..15: 0
// => D[p][q] = ||p||^2 - 2 p.q + eps, |eps| <= ~0.14 worst case
// (dropped ml*ql <= 0.006, pw residual <= 0.003, f32 accum rounding
// <= ~0.13). DELTA = 0.5 >= 2E covers the ballot mask.
//
// Fragment layout (R5-verified on HW by the passing refcheck):
//   A: lane l -> row l&31, k = 8*(l>>5) + j   (j = elem 0..7)
//   B: lane l -> col l&31, k = 8*(l>>5) + j
//   C/D: col = lane&31, row = (reg&3) + 8*(reg>>2) + 4*(lane>>5)
//
// Block = 256 thr = 4 waves, ONE slice, 256 queries (64/wave as two
// 32-col B-frags sharing each A-frag ds_read). A-frags staged in LDS
// (8 tiles x 64 lanes x 16B = 8KB), reused by all 4 waves.
__global__ __launch_bounds__(BLOCK) void values_kernel(
    const float* __restrict__ q, const float* __restrict__ r,
    float* __restrict__ smin, float4* __restrict__ r4,
    int N, int refsPerSlice)
{
    __shared__ half8 afrag[8][64];
    const int tid = threadIdx.x;
    const int s   = blockIdx.y;
    const int start = s * refsPerSlice;

    // ---- stage A-fragments (+ dual-store exact f32 r4 for the rescan) ----
    for (int j = tid; j < refsPerSlice; j += BLOCK) {
        const float px = r[3 * (start + j) + 0];
        const float py = r[3 * (start + j) + 1];
        const float pz = r[3 * (start + j) + 2];
        const float mx = -2.0f * px, my = -2.0f * py, mz = -2.0f * pz;
        const float pw = sumsq3(px, py, pz);
        const _Float16 mhx = (_Float16)mx, mhy = (_Float16)my, mhz = (_Float16)mz;
        const _Float16 mlx = (_Float16)(mx - (float)mhx);
        const _Float16 mly = (_Float16)(my - (float)mhy);
        const _Float16 mlz = (_Float16)(mz - (float)mhz);
        const _Float16 pwh = (_Float16)pw;
        const _Float16 pwl = (_Float16)(pw - (float)pwh);
        half8 lo, hi;
        lo[0] = mhx; lo[1] = mhy; lo[2] = mhz; lo[3] = mhx;
        lo[4] = mhy; lo[5] = mhz; lo[6] = mlx; lo[7] = mly;
        hi[0] = mlz; hi[1] = pwh; hi[2] = pwl; hi[3] = (_Float16)0;
        hi[4] = (_Float16)0; hi[5] = (_Float16)0; hi[6] = (_Float16)0; hi[7] = (_Float16)0;
        afrag[j >> 5][(j & 31)]      = lo;   // k 0..7 half
        afrag[j >> 5][32 + (j & 31)] = hi;   // k 8..15 half
        if (blockIdx.x == 0)   // bit-identical to previous rounds' r4
            r4[start + j] = make_float4(mx, my, mz, pw);
    }
    __syncthreads();

    // ---- wave compute: 64 queries/wave = two 32-col B operands ----
    const int lane = tid & 63, wave = tid >> 6, col = lane & 31;
    const int q0 = blockIdx.x * 256 + wave * 64 + col;
    const int q1 = q0 + 32;

    const float a0x = q[q0 * 3 + 0], a0y = q[q0 * 3 + 1], a0z = q[q0 * 3 + 2];
    const float a1x = q[q1 * 3 + 0], a1y = q[q1 * 3 + 1], a1z = q[q1 * 3 + 2];
    const float an0 = sumsq3(a0x, a0y, a0z);
    const float an1 = sumsq3(a1x, a1y, a1z);

    const _Float16 q0hx = (_Float16)a0x, q0hy = (_Float16)a0y, q0hz = (_Float16)a0z;
    const _Float16 q0lx = (_Float16)(a0x - (float)q0hx);
    const _Float16 q0ly = (_Float16)(a0y - (float)q0hy);
    const _Float16 q0lz = (_Float16)(a0z - (float)q0hz);
    const _Float16 q1hx = (_Float16)a1x, q1hy = (_Float16)a1y, q1hz = (_Float16)a1z;
    const _Float16 q1lx = (_Float16)(a1x - (float)q1hx);
    const _Float16 q1ly = (_Float16)(a1y - (float)q1hy);
    const _Float16 q1lz = (_Float16)(a1z - (float)q1hz);
    const _Float16 one = (_Float16)1.0f, zer = (_Float16)0.0f;

    half8 b0, b1;
    if (lane < 32) {   // k 0..7 half of the B column
        b0[0]=q0hx; b0[1]=q0hy; b0[2]=q0hz; b0[3]=q0lx; b0[4]=q0ly; b0[5]=q0lz; b0[6]=q0hx; b0[7]=q0hy;
        b1[0]=q1hx; b1[1]=q1hy; b1[2]=q1hz; b1[3]=q1lx; b1[4]=q1ly; b1[5]=q1lz; b1[6]=q1hx; b1[7]=q1hy;
    } else {           // k 8..15 half
        b0[0]=q0hz; b0[1]=one; b0[2]=one; b0[3]=zer; b0[4]=zer; b0[5]=zer; b0[6]=zer; b0[7]=zer;
        b1[0]=q1hz; b1[1]=one; b1[2]=one; b1[3]=zer; b1[4]=zer; b1[5]=zer; b1[6]=zer; b1[7]=zer;
    }

    const f32x16 Z = {0.f,0.f,0.f,0.f,0.f,0.f,0.f,0.f,0.f,0.f,0.f,0.f,0.f,0.f,0.f,0.f};
    float rm0 = __builtin_inff(), rm1 = __builtin_inff();
    const int nt = refsPerSlice >> 5;
#pragma unroll 4
    for (int t = 0; t < nt; ++t) {
        const half8 af = afrag[t][lane];                       // ds_read_b128
        const f32x16 c0 = __builtin_amdgcn_mfma_f32_32x32x16_f16(af, b0, Z, 0, 0, 0);
        const f32x16 c1 = __builtin_amdgcn_mfma_f32_32x32x16_f16(af, b1, Z, 0, 0, 0);
        rm0 = fminf(rm0, fold16(c0));
        rm1 = fminf(rm1, fold16(c1));
    }
    // lanes l and l^32 hold complementary ROW halves of the same col
    rm0 = fminf(rm0, __shfl_xor(rm0, 32));
    rm1 = fminf(rm1, __shfl_xor(rm1, 32));

    if (lane < 32) smin[(size_t)q0 * S + s] = an0 + rm0;
    else           smin[(size_t)q1 * S + s] = an1 + rm1;
}

// Pass 2: ONE WAVE PER QUERY, all in-register:
//  A) lane s reads slice s's (approx) min; val3-butterfly 3 smallest.
//  B) mask = ballot(v <= g2 + DELTA) — covers every slice containing a
//     true top-3 member. Cooperative EXACT rescan from r4 (bit-exact
//     reference rounding; see R3 proof), per-lane strict-< top-3.
//  MERGE (R6 rewrite — the old lex3 butterfly was ~486 VALU/wave):
//     values first via cheap med3 val3-butterfly (multiset-correct),
//     then indices via 3 u32 min-reduces with exclusion. Correct because:
//       (a) each ref index is scanned by exactly ONE lane (lane-partitioned
//           idx) and once per lane => global index uniqueness;
//       (b) strict-< insertion keeps equal values in ascending-index slot
//           order, so a lane's FIRST slot matching g_k holds its smallest
//           matching index;
//       (c) exclusions (idx != idxPrev) resolve exact-value ties across
//           slots/lanes, reproducing lax.top_k's stable index order; an
//           exclusion can never misfire on a foreign candidate since its
//           value-match fails first (uniqueness).
//  C) lane 0: rounding-exact weights + flow gather + store.
__global__ __launch_bounds__(BLOCK, 4) void rescan_kernel(
    const float* __restrict__ q, const float4* __restrict__ r4,
    const float* __restrict__ smin, const float* __restrict__ flow,
    float* __restrict__ out, int N, int refsPerSlice)
{
    const int lane = threadIdx.x & 63;
    const int qi   = blockIdx.x * (BLOCK / 64) + (threadIdx.x >> 6);

    const float a0 = q[qi * 3 + 0];
    const float a1 = q[qi * 3 + 1];
    const float a2 = q[qi * 3 + 2];
    const float an = sumsq3(a0, a1, a2);

    // --- A: coalesced min load + butterfly 3-smallest reduce ---
    const float v = smin[(size_t)qi * S + lane];
    float g0 = v, g1 = __builtin_inff(), g2 = __builtin_inff();
#pragma unroll
    for (int m = 1; m < 64; m <<= 1) {
        const float e0 = __shfl_xor(g0, m);
        const float e1 = __shfl_xor(g1, m);
        const float e2 = __shfl_xor(g2, m);
        val3_push(g0, g1, g2, e0);
        val3_push(g0, g1, g2, e1);
        val3_push(g0, g1, g2, e2);
    }

    unsigned long long mask = __ballot(v <= g2 + DELTA);

    // --- B: cooperative exact rescan of contributing slices ---
    float d0 = __builtin_inff(), d1 = __builtin_inff(), d2 = __builtin_inff();
    int   i0 = 0x7fffffff, i1 = 0x7fffffff, i2 = 0x7fffffff;
    const int K = refsPerSlice >> 6;       // refs per lane per slice

    while (mask) {
        const int s = (int)__builtin_ctzll(mask);
        mask &= mask - 1;
        const int base = s * refsPerSlice;
#pragma unroll 4
        for (int k = 0; k < K; ++k) {
            const int idx = base + lane + (k << 6);   // ascending per lane
            const float4 b = r4[idx];                 // (-2x,-2y,-2z,||b||^2)
            const float d = __builtin_fmaf(a2, b.z,
                            __builtin_fmaf(a1, b.y, mul_rn(a0, b.x)));
            const float sq = add_rn(d, add_rn(an, b.w));   // == reference fma(-2,dot,s)
            const bool c0 = sq < d0;
            const bool c1 = sq < d1;
            const bool c2 = sq < d2;
            i2 = c1 ? i1 : (c2 ? idx : i2);
            d2 = c1 ? d1 : (c2 ? sq  : d2);
            i1 = c0 ? i0 : (c1 ? idx : i1);
            d1 = c0 ? d0 : (c1 ? sq  : d1);
            i0 = c0 ? idx : i0;
            d0 = c0 ? sq  : d0;
        }
    }

    // --- MERGE: values via val3 butterfly, indices via excluded min-reduce ---
    float m0 = d0, m1 = d1, m2 = d2;       // per-lane sorted candidates
#pragma unroll
    for (int m = 1; m < 64; m <<= 1) {
        const float e0 = __shfl_xor(m0, m);
        const float e1 = __shfl_xor(m1, m);
        const float e2 = __shfl_xor(m2, m);
        val3_push(m0, m1, m2, e0);
        val3_push(m0, m1, m2, e1);
        val3_push(m0, m1, m2, e2);
    }
    const int INF = 0x7fffffff;
    int c = (d0 == m0) ? i0 : (d1 == m0) ? i1 : (d2 == m0) ? i2 : INF;
    const int x0 = wave_min_i(c);
    c = (d0 == m1 && i0 != x0) ? i0
      : (d1 == m1 && i1 != x0) ? i1
      : (d2 == m1 && i2 != x0) ? i2 : INF;
    const int x1 = wave_min_i(c);
    c = (d0 == m2 && i0 != x0 && i0 != x1) ? i0
      : (d1 == m2 && i1 != x0 && i1 != x1) ? i1
      : (d2 == m2 && i2 != x0 && i2 != x1) ? i2 : INF;
    const int x2 = wave_min_i(c);

    // --- C: epilogue (rounding-exact, matches reference op order) ---
    if (lane == 0) {
        const float t0 = sqrtf(fmaxf(m0, 1e-12f));
        const float t1 = sqrtf(fmaxf(m1, 1e-12f));
        const float t2 = sqrtf(fmaxf(m2, 1e-12f));
        const float w0r = 1.0f / add_rn(t0, 1e-8f);
        const float w1r = 1.0f / add_rn(t1, 1e-8f);
        const float w2r = 1.0f / add_rn(t2, 1e-8f);
        const float wsum = add_rn(add_rn(w0r, w1r), w2r);
        const float w0 = w0r / wsum;
        const float w1 = w1r / wsum;
        const float w2 = w2r / wsum;

        const float f00 = flow[3 * x0 + 0], f01 = flow[3 * x0 + 1], f02 = flow[3 * x0 + 2];
        const float f10 = flow[3 * x1 + 0], f11 = flow[3 * x1 + 1], f12 = flow[3 * x1 + 2];
        const float f20 = flow[3 * x2 + 0], f21 = flow[3 * x2 + 1], f22 = flow[3 * x2 + 2];

        out[qi * 3 + 0] = add_rn(add_rn(mul_rn(w0, f00), mul_rn(w1, f10)), mul_rn(w2, f20));
        out[qi * 3 + 1] = add_rn(add_rn(mul_rn(w0, f01), mul_rn(w1, f11)), mul_rn(w2, f21));
        out[qi * 3 + 2] = add_rn(add_rn(mul_rn(w0, f02), mul_rn(w1, f12)), mul_rn(w2, f22));
    }
}

extern "C" void kernel_launch(void* const* d_in, const int* in_sizes, int n_in,
                              void* d_out, int out_size, void* d_ws, size_t ws_size,
                              hipStream_t stream) {
    const float* q    = (const float*)d_in[0];
    const float* r    = (const float*)d_in[1];
    const float* flow = (const float*)d_in[2];
    // d_in[3] is k (==3), hard-coded.

    const int N = in_sizes[0] / 3;
    const int M = in_sizes[1] / 3;

    // ws layout: [smin: N*S floats][r4: M float4]
    const int refsPerSlice = M / S;
    float*  smin = (float*)d_ws;
    float4* r4   = (float4*)((char*)d_ws + (size_t)N * S * sizeof(float));
    (void)ws_size;

    dim3 grid1(N / 256, S);
    values_kernel<<<grid1, BLOCK, 0, stream>>>(q, r, smin, r4, N, refsPerSlice);

    rescan_kernel<<<N / (BLOCK / 64), BLOCK, 0, stream>>>(
        q, r4, smin, flow, (float*)d_out, N, refsPerSlice);
}